// Round 1
// baseline (176.796 us; speedup 1.0000x reference)
//
#include <hip/hip_runtime.h>

// Problem: y[b,c,0,h,w] = x[b,c,0,h,w]
//          y[b,c,n,h,w] = 0.3*x[b,c,n,h,w] + 0.7*y[b,c,n-1,h,w]
// Shapes: x,y = [4, 3, 32, 256, 256] fp32. Recurrence along axis 2 (N=32).
// Memory-bound: 201 MB total traffic -> ~32 us floor at 6.3 TB/s.

constexpr int   BC   = 4 * 3;        // fused batch*channel
constexpr int   NFR  = 32;           // frames (recurrence length)
constexpr int   HW4  = (256 * 256) / 4;  // float4 elements per frame-plane
constexpr float WF   = 0.3f;
constexpr float OMW  = 1.0f - WF;

__global__ __launch_bounds__(256) void recfilt_kernel(const float4* __restrict__ x,
                                                      float4* __restrict__ y) {
    const int p  = blockIdx.x * blockDim.x + threadIdx.x;   // chain id, [0, BC*HW4)
    const int bc = p >> 14;          // p / HW4  (HW4 = 16384 = 2^14)
    const int hw = p & (HW4 - 1);    // p % HW4
    const long base = (long)bc * NFR * HW4 + hw;

    float4 acc = x[base];
    y[base] = acc;
#pragma unroll
    for (int n = 1; n < NFR; ++n) {
        const long idx = base + (long)n * HW4;
        float4 xv = x[idx];
        acc.x = WF * xv.x + OMW * acc.x;
        acc.y = WF * xv.y + OMW * acc.y;
        acc.z = WF * xv.z + OMW * acc.z;
        acc.w = WF * xv.w + OMW * acc.w;
        y[idx] = acc;
    }
}

extern "C" void kernel_launch(void* const* d_in, const int* in_sizes, int n_in,
                              void* d_out, int out_size, void* d_ws, size_t ws_size,
                              hipStream_t stream) {
    const float4* x = (const float4*)d_in[0];
    float4*       y = (float4*)d_out;
    const int chains = BC * HW4;               // 196,608
    const int block  = 256;
    const int grid   = chains / block;         // 768
    recfilt_kernel<<<grid, block, 0, stream>>>(x, y);
}